// Round 7
// baseline (173.570 us; speedup 1.0000x reference)
//
#include <hip/hip_runtime.h>

#define NB 8
#define NC 256
#define NL 2048
#define SCALE 0.0625f   // C^-0.5 = 1/16

typedef __attribute__((ext_vector_type(8))) __bf16 bf16x8;
typedef __attribute__((ext_vector_type(4))) float f32x4;
typedef __attribute__((ext_vector_type(4))) unsigned int u32x4;
typedef __attribute__((ext_vector_type(4))) unsigned short u16x4;
typedef __attribute__((ext_vector_type(8))) unsigned short u16x8;

// round-to-nearest-even fp32 -> bf16 bits
static __device__ __forceinline__ unsigned short f2b(float f) {
    unsigned int u = __builtin_bit_cast(unsigned int, f);
    u += 0x7fffu + ((u >> 16) & 1u);
    return (unsigned short)(u >> 16);
}

// ---------------------------------------------------------------------------
// wconv: W fp32 [o][c] -> frag-major bf16 A-fragments for 16x16x32 MFMA.
// (verbatim R6)
// ---------------------------------------------------------------------------
__global__ void wconv_kernel(const float* __restrict__ Wq,
                             const float* __restrict__ Wk,
                             const float* __restrict__ Wv,
                             unsigned short* __restrict__ Wbf)
{
    const int fid  = blockIdx.x * 4 + (threadIdx.x >> 6);   // 0..383
    const int lane = threadIdx.x & 63;
    const int mat  = fid >> 7;          // 128 frags per mat
    const int oT   = (fid >> 3) & 15;
    const int kt   = fid & 7;
    const float* W = (mat == 0) ? Wq : (mat == 1) ? Wk : Wv;
    const int o = oT * 16 + (lane & 15);
    const int c = kt * 32 + (lane >> 4) * 8;
    float4 a  = *(const float4*)&W[(size_t)o * NC + c];
    float4 b2 = *(const float4*)&W[(size_t)o * NC + c + 4];
    u16x8 p = {f2b(a.x), f2b(a.y), f2b(a.z), f2b(a.w),
               f2b(b2.x), f2b(b2.y), f2b(b2.z), f2b(b2.w)};
    *(u16x8*)&Wbf[(size_t)fid * 512 + lane * 8] = p;
}

// ---------------------------------------------------------------------------
// qkv_fused (verbatim R6 control). grid 256, block 512.
// ---------------------------------------------------------------------------
__global__ __launch_bounds__(512, 2) void qkv_fused(
    const float* __restrict__ x,
    const unsigned short* __restrict__ Wbf,
    const float* __restrict__ bq, const float* __restrict__ bk,
    const float* __restrict__ bv,
    unsigned short* __restrict__ qT, unsigned short* __restrict__ kT,
    unsigned short* __restrict__ vo)
{
    const int raw = blockIdx.x;
    const int b   = raw & 7;            // XCD-pinned batch
    const int lt0 = (raw >> 3) * 64;
    const int t    = threadIdx.x;
    const int w    = t >> 6;
    const int lane = t & 63;
    const int ln15 = lane & 15;
    const int quad = lane >> 4;

    __shared__ __align__(16) unsigned short XT[64 * 256];   // [l][c] swz, 32 KB

    {
        const int c  = t >> 1;          // 0..255
        const int hh = t & 1;           // l-half
        const float* xr = &x[((size_t)(b * NC + c)) * NL + lt0 + hh * 32];
        const int cc = c >> 3, c7 = c & 7;
        #pragma unroll
        for (int j = 0; j < 8; ++j) {
            float4 xv = *(const float4*)&xr[j * 4];
            const int lb = hh * 32 + j * 4;
            unsigned short e0 = f2b(xv.x), e1 = f2b(xv.y),
                           e2 = f2b(xv.z), e3 = f2b(xv.w);
            XT[(lb + 0) * 256 + (cc ^ ((lb + 0) & 15)) * 8 + c7] = e0;
            XT[(lb + 1) * 256 + (cc ^ ((lb + 1) & 15)) * 8 + c7] = e1;
            XT[(lb + 2) * 256 + (cc ^ ((lb + 2) & 15)) * 8 + c7] = e2;
            XT[(lb + 3) * 256 + (cc ^ ((lb + 3) & 15)) * 8 + c7] = e3;
        }
    }
    __syncthreads();

    bf16x8 xf[4][8];
    #pragma unroll
    for (int lt = 0; lt < 4; ++lt) {
        const int l = lt * 16 + ln15;
        #pragma unroll
        for (int kt = 0; kt < 8; ++kt) {
            const int kc = kt * 4 + quad;
            const int pos = kc ^ (l & 15);
            xf[lt][kt] = __builtin_bit_cast(bf16x8, *(const u32x4*)&XT[l * 256 + pos * 8]);
        }
    }

    #pragma unroll
    for (int mat = 0; mat < 3; ++mat) {
        const float* bias = (mat == 0) ? bq : (mat == 1) ? bk : bv;
        float bvals[2][4];
        #pragma unroll
        for (int ot = 0; ot < 2; ++ot)
            #pragma unroll
            for (int r = 0; r < 4; ++r)
                bvals[ot][r] = bias[w * 32 + ot * 16 + quad * 4 + r];

        f32x4 acc[2][4];
        #pragma unroll
        for (int i = 0; i < 2; ++i)
            #pragma unroll
            for (int j = 0; j < 4; ++j) acc[i][j] = f32x4{0.f, 0.f, 0.f, 0.f};

        const size_t wb = ((size_t)(mat * 16 + w * 2) * 8) * 512 + lane * 8;
        #pragma unroll
        for (int kt = 0; kt < 8; ++kt) {
            bf16x8 wf0 = __builtin_bit_cast(bf16x8, *(const u32x4*)&Wbf[wb + (size_t)kt * 512]);
            bf16x8 wf1 = __builtin_bit_cast(bf16x8, *(const u32x4*)&Wbf[wb + (size_t)(8 + kt) * 512]);
            #pragma unroll
            for (int lt = 0; lt < 4; ++lt) {
                acc[0][lt] = __builtin_amdgcn_mfma_f32_16x16x32_bf16(wf0, xf[lt][kt], acc[0][lt], 0, 0, 0);
                acc[1][lt] = __builtin_amdgcn_mfma_f32_16x16x32_bf16(wf1, xf[lt][kt], acc[1][lt], 0, 0, 0);
            }
        }

        if (mat < 2) {
            unsigned short* out = (mat == 0) ? qT : kT;
            #pragma unroll
            for (int ot = 0; ot < 2; ++ot) {
                const int o_base = w * 32 + ot * 16 + quad * 4;
                #pragma unroll
                for (int lt = 0; lt < 4; ++lt) {
                    const int l = lt0 + lt * 16 + ln15;
                    u16x4 pk;
                    #pragma unroll
                    for (int r = 0; r < 4; ++r)
                        pk[r] = f2b(acc[ot][lt][r] + bvals[ot][r]);
                    *(u16x4*)&out[((size_t)(b * NL + l)) * NC + o_base] = pk;
                }
            }
        } else {
            #pragma unroll
            for (int ot = 0; ot < 2; ++ot)
                #pragma unroll
                for (int lt = 0; lt < 4; ++lt) {
                    const int l = lt0 + lt * 16 + ln15;
                    #pragma unroll
                    for (int r = 0; r < 4; ++r) {
                        const int o = w * 32 + ot * 16 + quad * 4 + r;
                        vo[((size_t)(b * NC + o)) * NL + l] = f2b(acc[ot][lt][r] + bvals[ot][r]);
                    }
                }
        }
    }
}

// ---------------------------------------------------------------------------
// attn: 32-query blocks. grid 512 (b=raw&7, lt32), block 256 = 4 waves
// (qg 0..1 x kg 0..1). Single-buffered K/V (68 KB LDS) -> 2 blocks/CU;
// barrier scope halves, cross-block overlap hides staging drain.
// All fragment/swizzle code identical to R5 (verified).
// ---------------------------------------------------------------------------
__global__ __launch_bounds__(256, 2) void attn_kernel(
    const unsigned short* __restrict__ qT,
    const unsigned short* __restrict__ kT,
    const unsigned short* __restrict__ v,
    const float* __restrict__ x,
    float* __restrict__ out)
{
    const int raw  = blockIdx.x;
    const int b    = raw & 7;          // XCD-pinned batch
    const int l0   = (raw >> 3) * 32;
    const int t    = threadIdx.x;
    const int w    = t >> 6;
    const int lane = t & 63;
    const int ln15 = lane & 15;
    const int quad = lane >> 4;
    const int qg   = w & 1;            // query group (16 rows)
    const int kg   = w >> 1;           // key half (32 keys)

    __shared__ __align__(16) char smem[69888];
    unsigned short* Klds = (unsigned short*)smem;            // 32 KB [n][c] swz
    unsigned short* Vlds = (unsigned short*)(smem + 32768);  // 32 KB [c][j] swz
    unsigned short* Plds = (unsigned short*)(smem + 65536);  //  4 KB (32x64)
    float* denomP = (float*)(smem + 69632);                  // 2*32 f32
    float (*ctxbuf)[36] = (float(*)[36])smem;                // epilogue alias, 36 KB

    // ---- Q fragments resident: rows l0 + qg*16 + ln15 ----
    bf16x8 qf[8];
    {
        const size_t qrow = ((size_t)b * NL + l0 + qg * 16 + ln15) * NC;
        #pragma unroll
        for (int kt = 0; kt < 8; ++kt)
            qf[kt] = __builtin_bit_cast(bf16x8,
                        *(const u32x4*)&qT[qrow + kt * 32 + quad * 8]);
    }

    f32x4 ctx[16];
    #pragma unroll
    for (int i = 0; i < 16; ++i) ctx[i] = f32x4{0.f, 0.f, 0.f, 0.f};
    float dacc[4] = {0.f, 0.f, 0.f, 0.f};

    for (int mt = 0; mt < 32; ++mt) {
        const int m0 = mt * 64;
        __syncthreads();   // previous tile's LDS reads complete

        // ---- stage K tile (64 rows x 512B) ----
        #pragma unroll
        for (int s = 0; s < 8; ++s) {
            const int il = w * 8 + s;
            const int n  = il * 2 + (lane >> 5);
            const int g  = (lane & 31) ^ (n & 15);
            const unsigned short* gp = &kT[((size_t)b * NL + m0 + n) * NC + g * 8];
            __builtin_amdgcn_global_load_lds(
                (const __attribute__((address_space(1))) unsigned int*)gp,
                (__attribute__((address_space(3))) unsigned int*)&Klds[il * 512],
                16, 0, 0);
        }
        // ---- stage V tile (256 rows x 128B) ----
        #pragma unroll
        for (int s = 0; s < 8; ++s) {
            const int il = w * 8 + s;
            const int c  = il * 8 + (lane >> 3);
            const int g  = (lane & 7) ^ (c & 7);
            const unsigned short* gp = &v[((size_t)(b * NC + c)) * NL + m0 + g * 8];
            __builtin_amdgcn_global_load_lds(
                (const __attribute__((address_space(1))) unsigned int*)gp,
                (__attribute__((address_space(3))) unsigned int*)&Vlds[il * 512],
                16, 0, 0);
        }
        __syncthreads();   // tiles visible

        // ---- S = Q^T K (this wave: 16 q x 32 keys of half kg) ----
        f32x4 sacc[2];
        sacc[0] = f32x4{0.f, 0.f, 0.f, 0.f};
        sacc[1] = f32x4{0.f, 0.f, 0.f, 0.f};
        #pragma unroll
        for (int nt = 0; nt < 2; ++nt) {
            const int n = kg * 32 + nt * 16 + ln15;
            #pragma unroll
            for (int kt = 0; kt < 8; ++kt) {
                const int p = (kt * 4 + quad) ^ ln15;
                bf16x8 bf = __builtin_bit_cast(bf16x8,
                              *(const u32x4*)&Klds[n * 256 + p * 8]);
                sacc[nt] = __builtin_amdgcn_mfma_f32_16x16x32_bf16(
                               qf[kt], bf, sacc[nt], 0, 0, 0);
            }
        }

        // ---- exp (no max-sub), partial row sums, P -> LDS (wave-local) ----
        float rs[4] = {0.f, 0.f, 0.f, 0.f};
        #pragma unroll
        for (int nt = 0; nt < 2; ++nt) {
            #pragma unroll
            for (int r = 0; r < 4; ++r) {
                float e = __expf(sacc[nt][r] * SCALE);
                rs[r] += e;
                const int ip = qg * 16 + quad * 4 + r;     // 0..31
                const int j  = kg * 32 + nt * 16 + ln15;
                const int pc = (j >> 3) ^ (ip & 7);
                Plds[ip * 64 + pc * 8 + (j & 7)] = f2b(e);
            }
        }
        #pragma unroll
        for (int r = 0; r < 4; ++r) {
            rs[r] += __shfl_xor(rs[r], 1, 64);
            rs[r] += __shfl_xor(rs[r], 2, 64);
            rs[r] += __shfl_xor(rs[r], 4, 64);
            rs[r] += __shfl_xor(rs[r], 8, 64);
            dacc[r] += rs[r];
        }

        // ---- PV: ctx[q][c] partial over this wave's 32 j ----
        bf16x8 pf;
        {
            const int m = qg * 16 + ln15;
            const int p = (kg * 4 + quad) ^ (m & 7);
            pf = __builtin_bit_cast(bf16x8, *(const u32x4*)&Plds[m * 64 + p * 8]);
        }
        #pragma unroll
        for (int ct = 0; ct < 16; ++ct) {
            const int c = ct * 16 + ln15;
            const int p = (kg * 4 + quad) ^ (c & 7);
            bf16x8 vb = __builtin_bit_cast(bf16x8,
                          *(const u32x4*)&Vlds[c * 64 + p * 8]);
            ctx[ct] = __builtin_amdgcn_mfma_f32_16x16x32_bf16(
                          pf, vb, ctx[ct], 0, 0, 0);
        }
    }

    // ---- epilogue: combine kg halves, normalize, residual, store ----
    __syncthreads();   // all waves done with K/V LDS before ctxbuf aliases it
    if (kg == 1) {
        #pragma unroll
        for (int ct = 0; ct < 16; ++ct) {
            const int c = ct * 16 + ln15;
            #pragma unroll
            for (int r = 0; r < 4; ++r)
                ctxbuf[c][qg * 16 + quad * 4 + r] = ctx[ct][r];
        }
    }
    if (ln15 == 0) {
        #pragma unroll
        for (int r = 0; r < 4; ++r)
            denomP[kg * 32 + qg * 16 + quad * 4 + r] = dacc[r];
    }
    __syncthreads();
    if (kg == 0) {
        float rinv[4];
        #pragma unroll
        for (int r = 0; r < 4; ++r) {
            const int ql = qg * 16 + quad * 4 + r;
            rinv[r] = 1.0f / (denomP[ql] + denomP[32 + ql]);
        }
        #pragma unroll
        for (int ct = 0; ct < 16; ++ct) {
            const int c = ct * 16 + ln15;
            #pragma unroll
            for (int r = 0; r < 4; ++r) {
                const int ql = qg * 16 + quad * 4 + r;
                ctxbuf[c][ql] = (ctx[ct][r] + ctxbuf[c][ql]) * rinv[r];
            }
        }
    }
    __syncthreads();

    // 256 c x 32 l fp32 stores + residual
    #pragma unroll
    for (int p = 0; p < 8; ++p) {
        const int f  = t + 256 * p;       // 0..2047
        const int c  = f >> 3;
        const int lg = (f & 7) * 4;
        const size_t idx = ((size_t)(b * NC + c)) * NL + l0 + lg;
        float4 xv = *(const float4*)&x[idx];
        float4 cv = *(const float4*)&ctxbuf[c][lg];
        float4 o = make_float4(cv.x + xv.x, cv.y + xv.y, cv.z + xv.z, cv.w + xv.w);
        *(float4*)&out[idx] = o;
    }
}

// ---------------------------------------------------------------------------
extern "C" void kernel_launch(void* const* d_in, const int* in_sizes, int n_in,
                              void* d_out, int out_size, void* d_ws, size_t ws_size,
                              hipStream_t stream) {
    const float* x  = (const float*)d_in[0];
    const float* Wq = (const float*)d_in[1];
    const float* bq = (const float*)d_in[2];
    const float* Wk = (const float*)d_in[3];
    const float* bk = (const float*)d_in[4];
    const float* Wv = (const float*)d_in[5];
    const float* bv = (const float*)d_in[6];
    float* out = (float*)d_out;

    const size_t plane = (size_t)NB * NC * NL;       // 4.19M elems
    unsigned short* qT  = (unsigned short*)d_ws;
    unsigned short* kT  = qT + plane;
    unsigned short* v   = kT + plane;
    unsigned short* Wbf = v + plane;                 // 384*512 elems

    wconv_kernel<<<96, 256, 0, stream>>>(Wq, Wk, Wv, Wbf);

    qkv_fused<<<256, 512, 0, stream>>>(x, Wbf, bq, bk, bv, qT, kT, v);

    attn_kernel<<<512, 256, 0, stream>>>(qT, kT, v, x, out);
}

// Round 8
// 165.978 us; speedup vs baseline: 1.0457x; 1.0457x over previous
//
#include <hip/hip_runtime.h>

#define NB 8
#define NC 256
#define NL 2048
#define SCALE 0.0625f   // C^-0.5 = 1/16

typedef __attribute__((ext_vector_type(8))) __bf16 bf16x8;
typedef __attribute__((ext_vector_type(4))) float f32x4;
typedef __attribute__((ext_vector_type(4))) unsigned int u32x4;
typedef __attribute__((ext_vector_type(4))) unsigned short u16x4;
typedef __attribute__((ext_vector_type(8))) unsigned short u16x8;

// round-to-nearest-even fp32 -> bf16 bits
static __device__ __forceinline__ unsigned short f2b(float f) {
    unsigned int u = __builtin_bit_cast(unsigned int, f);
    u += 0x7fffu + ((u >> 16) & 1u);
    return (unsigned short)(u >> 16);
}

// ---------------------------------------------------------------------------
// wconv: W fp32 [o][c] -> frag-major bf16 A-fragments for 16x16x32 MFMA.
// frag id f = (mat*16 + oT)*8 + kt. grid 96, block 256.
// ---------------------------------------------------------------------------
__global__ void wconv_kernel(const float* __restrict__ Wq,
                             const float* __restrict__ Wk,
                             const float* __restrict__ Wv,
                             unsigned short* __restrict__ Wbf)
{
    const int fid  = blockIdx.x * 4 + (threadIdx.x >> 6);   // 0..383
    const int lane = threadIdx.x & 63;
    const int mat  = fid >> 7;          // 128 frags per mat
    const int oT   = (fid >> 3) & 15;
    const int kt   = fid & 7;
    const float* W = (mat == 0) ? Wq : (mat == 1) ? Wk : Wv;
    const int o = oT * 16 + (lane & 15);
    const int c = kt * 32 + (lane >> 4) * 8;
    float4 a  = *(const float4*)&W[(size_t)o * NC + c];
    float4 b2 = *(const float4*)&W[(size_t)o * NC + c + 4];
    u16x8 p = {f2b(a.x), f2b(a.y), f2b(a.z), f2b(a.w),
               f2b(b2.x), f2b(b2.y), f2b(b2.z), f2b(b2.w)};
    *(u16x8*)&Wbf[(size_t)fid * 512 + lane * 8] = p;
}

// ---------------------------------------------------------------------------
// qkv_fused: grid 256 (b=raw&7, lt64), block 512.
// SPILL FIX vs R6/R7: __launch_bounds__(512,1) -> 256-VGPR budget (was
// (512,2) -> 128 cap -> scratch spill, MfmaUtil 0.1%, 125 us), and ot-outer
// loop keeps only acc[4] live. xf[4][8] (128 VGPR) stays resident across
// all 3 matrices.
// ---------------------------------------------------------------------------
__global__ __launch_bounds__(512, 1) void qkv_fused(
    const float* __restrict__ x,
    const unsigned short* __restrict__ Wbf,
    const float* __restrict__ bq, const float* __restrict__ bk,
    const float* __restrict__ bv,
    unsigned short* __restrict__ qT, unsigned short* __restrict__ kT,
    unsigned short* __restrict__ vo)
{
    const int raw = blockIdx.x;
    const int b   = raw & 7;            // XCD-pinned batch
    const int lt0 = (raw >> 3) * 64;
    const int t    = threadIdx.x;
    const int w    = t >> 6;
    const int lane = t & 63;
    const int ln15 = lane & 15;
    const int quad = lane >> 4;

    __shared__ __align__(16) unsigned short XT[64 * 256];   // [l][c] swz, 32 KB

    // ---- stage + transpose x tile: [256c x 64l] fp32 -> XT[l][c] bf16 ----
    {
        const int c  = t >> 1;          // 0..255
        const int hh = t & 1;           // l-half
        const float* xr = &x[((size_t)(b * NC + c)) * NL + lt0 + hh * 32];
        const int cc = c >> 3, c7 = c & 7;
        #pragma unroll
        for (int j = 0; j < 8; ++j) {
            float4 xv = *(const float4*)&xr[j * 4];
            const int lb = hh * 32 + j * 4;
            unsigned short e0 = f2b(xv.x), e1 = f2b(xv.y),
                           e2 = f2b(xv.z), e3 = f2b(xv.w);
            XT[(lb + 0) * 256 + (cc ^ ((lb + 0) & 15)) * 8 + c7] = e0;
            XT[(lb + 1) * 256 + (cc ^ ((lb + 1) & 15)) * 8 + c7] = e1;
            XT[(lb + 2) * 256 + (cc ^ ((lb + 2) & 15)) * 8 + c7] = e2;
            XT[(lb + 3) * 256 + (cc ^ ((lb + 3) & 15)) * 8 + c7] = e3;
        }
    }
    __syncthreads();

    // ---- X B-fragments resident: xf[lt][kt] ----
    bf16x8 xf[4][8];
    #pragma unroll
    for (int lt = 0; lt < 4; ++lt) {
        const int l = lt * 16 + ln15;
        #pragma unroll
        for (int kt = 0; kt < 8; ++kt) {
            const int kc = kt * 4 + quad;
            const int pos = kc ^ (l & 15);
            xf[lt][kt] = __builtin_bit_cast(bf16x8, *(const u32x4*)&XT[l * 256 + pos * 8]);
        }
    }

    // ---- 3 matrices x 2 o-subtiles; W frags streamed from L2 ----
    #pragma unroll
    for (int mat = 0; mat < 3; ++mat) {
        const float* bias = (mat == 0) ? bq : (mat == 1) ? bk : bv;
        #pragma unroll
        for (int ot = 0; ot < 2; ++ot) {
            f32x4 acc[4];
            #pragma unroll
            for (int j = 0; j < 4; ++j) acc[j] = f32x4{0.f, 0.f, 0.f, 0.f};

            const size_t wb = ((size_t)(mat * 16 + w * 2 + ot) * 8) * 512 + lane * 8;
            #pragma unroll
            for (int kt = 0; kt < 8; ++kt) {
                bf16x8 wf = __builtin_bit_cast(bf16x8, *(const u32x4*)&Wbf[wb + (size_t)kt * 512]);
                #pragma unroll
                for (int lt = 0; lt < 4; ++lt)
                    acc[lt] = __builtin_amdgcn_mfma_f32_16x16x32_bf16(wf, xf[lt][kt], acc[lt], 0, 0, 0);
            }

            float bvals[4];
            #pragma unroll
            for (int r = 0; r < 4; ++r)
                bvals[r] = bias[w * 32 + ot * 16 + quad * 4 + r];

            if (mat < 2) {
                unsigned short* out = (mat == 0) ? qT : kT;
                const int o_base = w * 32 + ot * 16 + quad * 4;
                #pragma unroll
                for (int lt = 0; lt < 4; ++lt) {
                    const int l = lt0 + lt * 16 + ln15;
                    u16x4 pk;
                    #pragma unroll
                    for (int r = 0; r < 4; ++r)
                        pk[r] = f2b(acc[lt][r] + bvals[r]);
                    *(u16x4*)&out[((size_t)(b * NL + l)) * NC + o_base] = pk;
                }
            } else {
                #pragma unroll
                for (int lt = 0; lt < 4; ++lt) {
                    const int l = lt0 + lt * 16 + ln15;
                    #pragma unroll
                    for (int r = 0; r < 4; ++r) {
                        const int o = w * 32 + ot * 16 + quad * 4 + r;
                        vo[((size_t)(b * NC + o)) * NL + l] = f2b(acc[lt][r] + bvals[r]);
                    }
                }
            }
        }
    }
}

// ---------------------------------------------------------------------------
// attn (VERBATIM R5, best measured at 74.9 us): grid 256 (b=raw&7, lt64),
// block 512 = 8 waves (qg x kg). Double-buffered K/V, one barrier/tile.
// ---------------------------------------------------------------------------
__global__ __launch_bounds__(512, 1) void attn_kernel(
    const unsigned short* __restrict__ qT,
    const unsigned short* __restrict__ kT,
    const unsigned short* __restrict__ v,
    const float* __restrict__ x,
    float* __restrict__ out)
{
    const int raw  = blockIdx.x;
    const int b    = raw & 7;
    const int l0   = (raw >> 3) * 64;
    const int t    = threadIdx.x;
    const int w    = t >> 6;
    const int lane = t & 63;
    const int ln15 = lane & 15;
    const int quad = lane >> 4;
    const int qg   = w & 3;
    const int kg   = w >> 2;

    __shared__ __align__(16) char smem[139776];
    unsigned short* Kb0 = (unsigned short*)smem;
    unsigned short* Kb1 = (unsigned short*)(smem + 32768);
    unsigned short* Vb0 = (unsigned short*)(smem + 65536);
    unsigned short* Vb1 = (unsigned short*)(smem + 98304);
    unsigned short* Plds = (unsigned short*)(smem + 131072);
    float* denomP = (float*)(smem + 139264);
    float (*ctxbuf)[68] = (float(*)[68])smem;

    bf16x8 qf[8];
    {
        const size_t qrow = ((size_t)b * NL + l0 + qg * 16 + ln15) * NC;
        #pragma unroll
        for (int kt = 0; kt < 8; ++kt)
            qf[kt] = __builtin_bit_cast(bf16x8,
                        *(const u32x4*)&qT[qrow + kt * 32 + quad * 8]);
    }

    f32x4 ctx[16];
    #pragma unroll
    for (int i = 0; i < 16; ++i) ctx[i] = f32x4{0.f, 0.f, 0.f, 0.f};
    float dacc[4] = {0.f, 0.f, 0.f, 0.f};

    auto stage = [&](int mt, unsigned short* Kd, unsigned short* Vd) {
        const int m0 = mt * 64;
        #pragma unroll
        for (int s = 0; s < 4; ++s) {
            const int il = w * 4 + s;
            const int n  = il * 2 + (lane >> 5);
            const int g  = (lane & 31) ^ (n & 15);
            const unsigned short* gp = &kT[((size_t)b * NL + m0 + n) * NC + g * 8];
            __builtin_amdgcn_global_load_lds(
                (const __attribute__((address_space(1))) unsigned int*)gp,
                (__attribute__((address_space(3))) unsigned int*)&Kd[il * 512],
                16, 0, 0);
        }
        #pragma unroll
        for (int s = 0; s < 4; ++s) {
            const int il = w * 4 + s;
            const int c  = il * 8 + (lane >> 3);
            const int g  = (lane & 7) ^ (c & 7);
            const unsigned short* gp = &v[((size_t)(b * NC + c)) * NL + m0 + g * 8];
            __builtin_amdgcn_global_load_lds(
                (const __attribute__((address_space(1))) unsigned int*)gp,
                (__attribute__((address_space(3))) unsigned int*)&Vd[il * 512],
                16, 0, 0);
        }
    };

    stage(0, Kb0, Vb0);
    __syncthreads();

    for (int mt = 0; mt < 32; ++mt) {
        if (mt < 31) {
            if (mt & 1) stage(mt + 1, Kb0, Vb0);
            else        stage(mt + 1, Kb1, Vb1);
        }
        const unsigned short* Kd = (mt & 1) ? Kb1 : Kb0;
        const unsigned short* Vd = (mt & 1) ? Vb1 : Vb0;

        f32x4 sacc[2];
        sacc[0] = f32x4{0.f, 0.f, 0.f, 0.f};
        sacc[1] = f32x4{0.f, 0.f, 0.f, 0.f};
        #pragma unroll
        for (int nt = 0; nt < 2; ++nt) {
            const int n = kg * 32 + nt * 16 + ln15;
            #pragma unroll
            for (int kt = 0; kt < 8; ++kt) {
                const int p = (kt * 4 + quad) ^ ln15;
                bf16x8 bf = __builtin_bit_cast(bf16x8,
                              *(const u32x4*)&Kd[n * 256 + p * 8]);
                sacc[nt] = __builtin_amdgcn_mfma_f32_16x16x32_bf16(
                               qf[kt], bf, sacc[nt], 0, 0, 0);
            }
        }

        float rs[4] = {0.f, 0.f, 0.f, 0.f};
        #pragma unroll
        for (int nt = 0; nt < 2; ++nt) {
            #pragma unroll
            for (int r = 0; r < 4; ++r) {
                float e = __expf(sacc[nt][r] * SCALE);
                rs[r] += e;
                const int ip = qg * 16 + quad * 4 + r;
                const int j  = kg * 32 + nt * 16 + ln15;
                const int pc = (j >> 3) ^ (ip & 7);
                Plds[ip * 64 + pc * 8 + (j & 7)] = f2b(e);
            }
        }
        #pragma unroll
        for (int r = 0; r < 4; ++r) {
            rs[r] += __shfl_xor(rs[r], 1, 64);
            rs[r] += __shfl_xor(rs[r], 2, 64);
            rs[r] += __shfl_xor(rs[r], 4, 64);
            rs[r] += __shfl_xor(rs[r], 8, 64);
            dacc[r] += rs[r];
        }

        bf16x8 pf;
        {
            const int m = qg * 16 + ln15;
            const int p = (kg * 4 + quad) ^ (m & 7);
            pf = __builtin_bit_cast(bf16x8, *(const u32x4*)&Plds[m * 64 + p * 8]);
        }
        #pragma unroll
        for (int ct = 0; ct < 16; ++ct) {
            const int c = ct * 16 + ln15;
            const int p = (kg * 4 + quad) ^ (c & 7);
            bf16x8 vb = __builtin_bit_cast(bf16x8,
                          *(const u32x4*)&Vd[c * 64 + p * 8]);
            ctx[ct] = __builtin_amdgcn_mfma_f32_16x16x32_bf16(
                          pf, vb, ctx[ct], 0, 0, 0);
        }

        __syncthreads();
    }

    if (kg == 1) {
        #pragma unroll
        for (int ct = 0; ct < 16; ++ct) {
            const int c = ct * 16 + ln15;
            #pragma unroll
            for (int r = 0; r < 4; ++r)
                ctxbuf[c][qg * 16 + quad * 4 + r] = ctx[ct][r];
        }
    }
    if (ln15 == 0) {
        #pragma unroll
        for (int r = 0; r < 4; ++r)
            denomP[kg * 64 + qg * 16 + quad * 4 + r] = dacc[r];
    }
    __syncthreads();
    if (kg == 0) {
        float rinv[4];
        #pragma unroll
        for (int r = 0; r < 4; ++r) {
            const int ql = qg * 16 + quad * 4 + r;
            rinv[r] = 1.0f / (denomP[ql] + denomP[64 + ql]);
        }
        #pragma unroll
        for (int ct = 0; ct < 16; ++ct) {
            const int c = ct * 16 + ln15;
            #pragma unroll
            for (int r = 0; r < 4; ++r) {
                const int ql = qg * 16 + quad * 4 + r;
                ctxbuf[c][ql] = (ctx[ct][r] + ctxbuf[c][ql]) * rinv[r];
            }
        }
    }
    __syncthreads();

    #pragma unroll
    for (int p = 0; p < 8; ++p) {
        const int f  = t + 512 * p;
        const int c  = f >> 4;
        const int lg = (f & 15) * 4;
        const size_t idx = ((size_t)(b * NC + c)) * NL + l0 + lg;
        float4 xv = *(const float4*)&x[idx];
        float4 cv = *(const float4*)&ctxbuf[c][lg];
        float4 o = make_float4(cv.x + xv.x, cv.y + xv.y, cv.z + xv.z, cv.w + xv.w);
        *(float4*)&out[idx] = o;
    }
}

// ---------------------------------------------------------------------------
extern "C" void kernel_launch(void* const* d_in, const int* in_sizes, int n_in,
                              void* d_out, int out_size, void* d_ws, size_t ws_size,
                              hipStream_t stream) {
    const float* x  = (const float*)d_in[0];
    const float* Wq = (const float*)d_in[1];
    const float* bq = (const float*)d_in[2];
    const float* Wk = (const float*)d_in[3];
    const float* bk = (const float*)d_in[4];
    const float* Wv = (const float*)d_in[5];
    const float* bv = (const float*)d_in[6];
    float* out = (float*)d_out;

    const size_t plane = (size_t)NB * NC * NL;       // 4.19M elems
    unsigned short* qT  = (unsigned short*)d_ws;
    unsigned short* kT  = qT + plane;
    unsigned short* v   = kT + plane;
    unsigned short* Wbf = v + plane;                 // 384*512 elems

    wconv_kernel<<<96, 256, 0, stream>>>(Wq, Wk, Wv, Wbf);

    qkv_fused<<<256, 512, 0, stream>>>(x, Wbf, bq, bk, bv, qT, kT, v);

    attn_kernel<<<256, 512, 0, stream>>>(qT, kT, v, x, out);
}